// Round 8
// baseline (8132.703 us; speedup 1.0000x reference)
//
#include <hip/hip_runtime.h>
#include <hip/hip_bf16.h>

// CustomLSTM: B=128, T=1024, D=256, U=256, fp32 in/out.
// Round 6 kernel, third submission (R6 container fail, R7 acquisition timeout;
// kernel has never run on HW).
// Theory: make the resident set FIT (rounds 2-5 were over the 256-reg cap:
// 184 pinned + 32 acc + ~60 working = 276 > 256 -> RA spilled/sank, VGPR=128).
//  - NREG=38 (152 pinned VGPRs), NLDS=18 (144 KB). The 8 homeless chunks
//    (ks=7) are re-streamed from L2 each step, issued early, hidden under MFMA.
//  - Fast elementwise: v_rcp/v_exp inline asm (no IEEE div sequences).
//    Per-active-CU VALUBusy was 52% -- divides were ~40% of it.
//  - Gate-phase split + hA double-buffer retained; static offsets hoisted.
// 8 blocks x 16 batches; no inter-block communication anywhere.

#define B_ 128
#define T_ 1024
#define D_ 256
#define U_ 256

#define NLDS 18          // chunks per wave in LDS   (144 KB block total)
#define NREG 38          // chunks per wave in VGPRs (152 VGPRs, asm-pinned)
// chunks q in [56,64) streamed from L2 each step (ks=7, both halves)

#define HALL ((size_t)B_ * T_ * U_)

using short8  = __attribute__((ext_vector_type(8))) short;   // 8 bf16 (4 VGPRs)
using float4v = __attribute__((ext_vector_type(4))) float;   // 4 fp32 acc

__device__ inline unsigned short f2bf(float f) {
    unsigned int u = __float_as_uint(f);
    unsigned int r = (u + 0x7FFFu + ((u >> 16) & 1u)) >> 16;
    return (unsigned short)r;
}
__device__ inline float bflo(unsigned int v) { return __uint_as_float(v << 16); }
__device__ inline float bfhi(unsigned int v) { return __uint_as_float(v & 0xffff0000u); }

// 1-instruction transcendentals (HW-interlocked on gfx9-class; no hazards).
__device__ __forceinline__ float fexp2(float x) {
    float r; asm("v_exp_f32 %0, %1" : "=v"(r) : "v"(x)); return r;
}
__device__ __forceinline__ float frcp(float x) {
    float r; asm("v_rcp_f32 %0, %1" : "=v"(r) : "v"(x)); return r;
}
__device__ __forceinline__ float sigm(float z) {
    return frcp(1.0f + fexp2(-1.44269504f * z));
}
__device__ __forceinline__ float tanh_f(float z) {
    return 1.0f - 2.0f * frcp(1.0f + fexp2(2.88539008f * z));
}

// ---------------------------------------------------------------------------
// Pack 8 matrices [256][256] fp32 (row k, col u) into bf16 MFMA B-fragments.
// chunk = (w*8 + ks)*8 + c8,  c8 = h*4 + g  (h = u-half, g = gate f/i/c/o).
// chunk = 512 shorts (64 lanes x 8).
// Lane l of chunk holds  M[k = ks*32 + (l>>4)*8 + j][u = w*32 + h*16 + (l&15)].
// pack0 (offset 0 shorts)      = Uf,Ui,Uc,Uo   (recurrent)
// pack1 (offset 262144 shorts) = Wf,Wi,Wc,Wo   (input proj)
// ---------------------------------------------------------------------------
__global__ __launch_bounds__(256) void pack_kernel(
    const float* __restrict__ Uf, const float* __restrict__ Ui,
    const float* __restrict__ Uc, const float* __restrict__ Uo,
    const float* __restrict__ Wf, const float* __restrict__ Wi,
    const float* __restrict__ Wc, const float* __restrict__ Wo,
    short* __restrict__ ws)
{
    int q = blockIdx.x * 256 + threadIdx.x;      // 0..65535
    int p     = q >> 15;                          // 0: U-pack, 1: W-pack
    int rem   = q & 32767;
    int chunk = rem >> 6;                         // 0..511
    int l     = rem & 63;
    int c8 = chunk & 7;
    int g  = c8 & 3;                              // gate (f,i,c,o)
    int h  = c8 >> 2;                             // u-half
    int ks = (chunk >> 3) & 7;
    int w  = chunk >> 6;

    const float* mats[8] = {Uf, Ui, Uc, Uo, Wf, Wi, Wc, Wo};
    const float* M = mats[p * 4 + g];

    int u = w * 32 + h * 16 + (l & 15);
    int k = ks * 32 + ((l >> 4) << 3);
    const float* s = M + (size_t)k * 256 + u;

    short8 fr;
#pragma unroll
    for (int j = 0; j < 8; ++j) fr[j] = (short)f2bf(s[(size_t)j * 256]);

    short* dst = ws + (size_t)p * 262144 + (size_t)chunk * 512 + l * 8;
    *reinterpret_cast<short8*>(dst) = fr;
}

// ---------------------------------------------------------------------------
// proj: zx[t][b][u][g] (bf16, g minor, bias folded) = sum_k x[b][t][k]*W_g[k][u] + b_g[u]
// M-tile = 64 rows per block; streams W-pack fragments from L2.
// ---------------------------------------------------------------------------
__global__ __launch_bounds__(512, 2) void proj_kernel(
    const float* __restrict__ x, const short* __restrict__ wpack,
    const float* __restrict__ bfv, const float* __restrict__ biv,
    const float* __restrict__ bcv, const float* __restrict__ bov,
    short* __restrict__ zx)
{
    __shared__ short aF[4 * 8 * 512];  // 4 M-sub x 8 ks chunks (32KB)
    const int tid = threadIdx.x;
    const int w = tid >> 6, l = tid & 63;
    const long m0 = (long)blockIdx.x * 64;

    // stage A fragments: x rows m0..m0+63, bf16
#pragma unroll
    for (int rep = 0; rep < 4; ++rep) {
        int slot = tid + rep * 512;      // 0..2047
        int ms = slot >> 9;
        int rem = slot & 511;
        int ks = rem >> 6;
        int ll = rem & 63;
        long mm = m0 + ms * 16 + (ll & 15);
        int k = ks * 32 + ((ll >> 4) << 3);
        const float* s = x + (size_t)mm * 256 + k;
        float4 v0 = *reinterpret_cast<const float4*>(s);
        float4 v1 = *reinterpret_cast<const float4*>(s + 4);
        short8 fr;
        fr[0] = (short)f2bf(v0.x); fr[1] = (short)f2bf(v0.y);
        fr[2] = (short)f2bf(v0.z); fr[3] = (short)f2bf(v0.w);
        fr[4] = (short)f2bf(v1.x); fr[5] = (short)f2bf(v1.y);
        fr[6] = (short)f2bf(v1.z); fr[7] = (short)f2bf(v1.w);
        *reinterpret_cast<short8*>(&aF[(ms * 8 + ks) * 512 + ll * 8]) = fr;
    }
    __syncthreads();

    float4v acc[4][8];
#pragma unroll
    for (int ms = 0; ms < 4; ++ms)
#pragma unroll
        for (int c8 = 0; c8 < 8; ++c8) acc[ms][c8] = (float4v){0.f, 0.f, 0.f, 0.f};

    const short* base = wpack + (size_t)w * 64 * 512;
#pragma unroll
    for (int ks = 0; ks < 8; ++ks) {
        short8 a[4];
#pragma unroll
        for (int ms = 0; ms < 4; ++ms)
            a[ms] = *reinterpret_cast<const short8*>(&aF[(ms * 8 + ks) * 512 + l * 8]);
#pragma unroll
        for (int c8 = 0; c8 < 8; ++c8) {
            short8 bfr = *reinterpret_cast<const short8*>(base + (size_t)(ks * 8 + c8) * 512 + l * 8);
#pragma unroll
            for (int ms = 0; ms < 4; ++ms)
                acc[ms][c8] = __builtin_amdgcn_mfma_f32_16x16x32_bf16(a[ms], bfr, acc[ms][c8], 0, 0, 0);
        }
    }

    // write zx: 4 gates packed per (m,u): 8 bytes; bias folded in fp32.
#pragma unroll
    for (int ms = 0; ms < 4; ++ms)
#pragma unroll
        for (int h = 0; h < 2; ++h)
#pragma unroll
            for (int j = 0; j < 4; ++j) {
                size_t mm = (size_t)(m0 + ms * 16 + ((l >> 4) << 2) + j);
                int u = w * 32 + h * 16 + (l & 15);
                size_t b = mm >> 10;          // mm = b*T + t
                size_t t = mm & 1023;
                unsigned int g0 = f2bf(acc[ms][h * 4 + 0][j] + bfv[u]);
                unsigned int g1 = f2bf(acc[ms][h * 4 + 1][j] + biv[u]);
                unsigned int g2 = f2bf(acc[ms][h * 4 + 2][j] + bcv[u]);
                unsigned int g3 = f2bf(acc[ms][h * 4 + 3][j] + bov[u]);
                uint2 v;
                v.x = g0 | (g1 << 16);
                v.y = g2 | (g3 << 16);
                *reinterpret_cast<uint2*>(zx + (t * B_ + b) * 1024 + (size_t)u * 4) = v;
            }
}

// ---------------------------------------------------------------------------
// Elementwise LSTM gate phase for one u-half: 4 outputs (j=0..3).
// ---------------------------------------------------------------------------
__device__ __forceinline__ void ew4(
    int t, const float4v ac[4], const uint2 zc[4], float* csth,
    short* dst, int raddr, float* __restrict__ out_t, const int* ooff,
    float* __restrict__ out, int bb0, int u)
{
#pragma unroll
    for (int j = 0; j < 4; ++j) {
        uint2 v = zc[j];
        float zf = ac[0][j] + bflo(v.x);
        float zi = ac[1][j] + bfhi(v.x);
        float zg = ac[2][j] + bflo(v.y);
        float zo = ac[3][j] + bfhi(v.y);
        float fg = sigm(zf), ig = sigm(zi), og = sigm(zo);
        float cg = tanh_f(zg);
        float cn = fg * csth[j] + ig * cg;
        csth[j] = cn;
        float hn = og * tanh_f(cn);

        out_t[ooff[j]] = hn;
        if (t == T_ - 1) {
            int bb = bb0 + j;
            out[HALL + (size_t)bb * 256 + u] = hn;
            out[HALL + (size_t)B_ * U_ + (size_t)bb * 256 + u] = cn;
        }
        dst[raddr + j * 8] = (short)f2bf(hn);
    }
}

// One full LSTM step: reads h A-frags from src, writes new ones to dst.
__device__ __forceinline__ void lstm_step(
    int t, const short* src, short* dst, const short* wl,
    const short8 (&wreg)[NREG], const short* baseU,
    const short* __restrict__ zx, float* __restrict__ out,
    float (&cst)[2][4],
    const int* zoffA, const int* zoffB, const int* ooffA, const int* ooffB,
    int rA, int rB, int b0, int w, int l, int rg, int u0)
{
    const short* zx_t = zx + (size_t)t * (B_ * 1024);
    float* out_t = out + (size_t)t * 256;
    const int bb0 = b0 + rg * 4;

    // stream ks=7 half-A chunks (q=56..59) -- issued first, used last in loop
    short8 sA[4];
#pragma unroll
    for (int g = 0; g < 4; ++g)
        sA[g] = *reinterpret_cast<const short8*>(baseU + (size_t)(56 + g) * 512);
    uint2 zcA[4];
#pragma unroll
    for (int j = 0; j < 4; ++j)
        zcA[j] = *reinterpret_cast<const uint2*>(zx_t + zoffA[j]);

    // ---- half A: u-low 16 cols, gates f,i,c,o ----
    float4v ac[4];
#pragma unroll
    for (int g = 0; g < 4; ++g) ac[g] = (float4v){0.f, 0.f, 0.f, 0.f};
#pragma unroll
    for (int ks = 0; ks < 8; ++ks) {
        short8 a = *reinterpret_cast<const short8*>(&src[ks * 512 + l * 8]);
#pragma unroll
        for (int g = 0; g < 4; ++g) {
            const int q = ks * 8 + g;
            short8 bv;
            if (q < NLDS)
                bv = *reinterpret_cast<const short8*>(&wl[(w * NLDS + q) * 512 + l * 8]);
            else if (q < NLDS + NREG)
                bv = wreg[q - NLDS];
            else
                bv = sA[g];                   // q = 56+g (ks==7)
            ac[g] = __builtin_amdgcn_mfma_f32_16x16x32_bf16(a, bv, ac[g], 0, 0, 0);
        }
    }

    // stream half-B ks=7 chunks (q=60..63) early; latency hides under ew4+MFMA
    short8 sB[4];
#pragma unroll
    for (int g = 0; g < 4; ++g)
        sB[g] = *reinterpret_cast<const short8*>(baseU + (size_t)(60 + g) * 512);
    uint2 zcB[4];
#pragma unroll
    for (int j = 0; j < 4; ++j)
        zcB[j] = *reinterpret_cast<const uint2*>(zx_t + zoffB[j]);

    ew4(t, ac, zcA, cst[0], dst, rA, out_t, ooffA, out, bb0, u0);

    // ---- half B: u-high 16 cols ----
    float4v ac2[4];
#pragma unroll
    for (int g = 0; g < 4; ++g) ac2[g] = (float4v){0.f, 0.f, 0.f, 0.f};
#pragma unroll
    for (int ks = 0; ks < 8; ++ks) {
        short8 a = *reinterpret_cast<const short8*>(&src[ks * 512 + l * 8]);
#pragma unroll
        for (int g = 0; g < 4; ++g) {
            const int q = ks * 8 + 4 + g;
            short8 bv;
            if (q < NLDS)
                bv = *reinterpret_cast<const short8*>(&wl[(w * NLDS + q) * 512 + l * 8]);
            else if (q < NLDS + NREG)
                bv = wreg[q - NLDS];
            else
                bv = sB[g];                   // q = 60+g (ks==7)
            ac2[g] = __builtin_amdgcn_mfma_f32_16x16x32_bf16(a, bv, ac2[g], 0, 0, 0);
        }
    }
    ew4(t, ac2, zcB, cst[1], dst, rB, out_t, ooffB, out, bb0, u0 + 16);
}

// ---------------------------------------------------------------------------
// Resident scan. 8 blocks x 512 threads; block owns batches [b0, b0+16).
// Chunks q<18 in LDS; 18<=q<56 pinned in VGPRs; q>=56 streamed from L2.
// ---------------------------------------------------------------------------
__global__ __launch_bounds__(512, 2) void lstm_scan_res(
    const float* __restrict__ h0, const float* __restrict__ c0,
    const short* __restrict__ upack, const short* __restrict__ zx,
    float* __restrict__ out)
{
    __shared__ short wlds[NLDS * 8 * 512];   // 144 KB weight chunks
    __shared__ short hAa[4096];              // 8 KB h A-fragments (even src)
    __shared__ short hAb[4096];              // 8 KB h A-fragments (odd src)

    const int tid = threadIdx.x;
    const int w = tid >> 6, l = tid & 63;
    const int b0 = blockIdx.x * 16;
    const int col = l & 15, rg = l >> 4;
    const int u0 = w * 32 + col;             // h=0 column
    const int u1 = u0 + 16;                  // h=1 column

    // one-time: stage this wave's LDS chunks and load its register chunks
    const short* baseU = upack + (size_t)w * 64 * 512 + (size_t)l * 8;
#pragma unroll
    for (int q = 0; q < NLDS; ++q)
        *reinterpret_cast<short8*>(&wlds[((size_t)w * NLDS + q) * 512 + l * 8]) =
            *reinterpret_cast<const short8*>(baseU + (size_t)q * 512);

    short8 wreg[NREG];
#pragma unroll
    for (int r = 0; r < NREG; ++r)
        wreg[r] = *reinterpret_cast<const short8*>(baseU + (size_t)(NLDS + r) * 512);
    // Pin: values become asm-outputs -> rematerializing from memory illegal ->
    // must stay live in registers. 152 regs; total pressure ~240 <= 256 cap.
#pragma unroll
    for (int r = 0; r < NREG; ++r)
        asm volatile("" : "+v"(wreg[r]));

    float cst[2][4];
#pragma unroll
    for (int j = 0; j < 4; ++j) {
        cst[0][j] = c0[(size_t)(b0 + rg * 4 + j) * 256 + u0];
        cst[1][j] = c0[(size_t)(b0 + rg * 4 + j) * 256 + u1];
    }

    // static per-thread offsets (loop-invariant)
    int zoffA[4], zoffB[4], ooffA[4], ooffB[4];
#pragma unroll
    for (int j = 0; j < 4; ++j) {
        int bb = b0 + rg * 4 + j;
        zoffA[j] = bb * 1024 + u0 * 4;
        zoffB[j] = bb * 1024 + u1 * 4;
        ooffA[j] = bb * (T_ * 256) + u0;
        ooffB[j] = bb * (T_ * 256) + u1;
    }
    const int rA = (u0 >> 5) * 512 + (rg * 4 + 16 * ((u0 >> 3) & 3)) * 8 + (u0 & 7);
    const int rB = (u1 >> 5) * 512 + (rg * 4 + 16 * ((u1 >> 3) & 3)) * 8 + (u1 & 7);

    // stage h0 as A-fragments into hAa (wave w stages ks-chunk w)
    {
        int ks = w;
        int bb = b0 + col;
        int k = ks * 32 + rg * 8;
        const float* s = h0 + (size_t)bb * 256 + k;
        float4 v0 = *reinterpret_cast<const float4*>(s);
        float4 v1 = *reinterpret_cast<const float4*>(s + 4);
        short8 fr;
        fr[0] = (short)f2bf(v0.x); fr[1] = (short)f2bf(v0.y);
        fr[2] = (short)f2bf(v0.z); fr[3] = (short)f2bf(v0.w);
        fr[4] = (short)f2bf(v1.x); fr[5] = (short)f2bf(v1.y);
        fr[6] = (short)f2bf(v1.z); fr[7] = (short)f2bf(v1.w);
        *reinterpret_cast<short8*>(&hAa[ks * 512 + l * 8]) = fr;
    }
    __syncthreads();

#pragma unroll 1
    for (int t = 0; t < T_; t += 2) {
        lstm_step(t,     hAa, hAb, wlds, wreg, baseU, zx, out, cst,
                  zoffA, zoffB, ooffA, ooffB, rA, rB, b0, w, l, rg, u0);
        __syncthreads();
        lstm_step(t + 1, hAb, hAa, wlds, wreg, baseU, zx, out, cst,
                  zoffA, zoffB, ooffA, ooffB, rA, rB, b0, w, l, rg, u0);
        __syncthreads();
    }
}

// ---------------------------------------------------------------------------
// Fallback fused scan (workspace too small for zx): streams U and W packs
// from L2 every step. Slow but correct. (Gate order: c8 = h*4 + g.)
// ---------------------------------------------------------------------------
__global__ __launch_bounds__(512, 2) void lstm_scan_fused(
    const float* __restrict__ x,
    const float* __restrict__ h0, const float* __restrict__ c0,
    const float* __restrict__ bfv, const float* __restrict__ biv,
    const float* __restrict__ bcv, const float* __restrict__ bov,
    const short* __restrict__ upack, const short* __restrict__ wpack,
    float* __restrict__ out)
{
    __shared__ short hA[4096];
    __shared__ short xA[4096];

    const int tid = threadIdx.x;
    const int w = tid >> 6, l = tid & 63;
    const int b0 = blockIdx.x * 16;
    const int col = l & 15, rg = l >> 4;

    float bias[4][2];
#pragma unroll
    for (int h = 0; h < 2; ++h) {
        int u = w * 32 + h * 16 + col;
        bias[0][h] = bfv[u]; bias[1][h] = biv[u];
        bias[2][h] = bcv[u]; bias[3][h] = bov[u];
    }
    float cst[2][4];
#pragma unroll
    for (int h = 0; h < 2; ++h)
#pragma unroll
        for (int j = 0; j < 4; ++j)
            cst[h][j] = c0[(size_t)(b0 + rg * 4 + j) * 256 + (w * 32 + h * 16 + col)];

    {
        int ks = w;
        int bb = b0 + col;
        int k = ks * 32 + rg * 8;
        const float* s = h0 + (size_t)bb * 256 + k;
        float4 v0 = *reinterpret_cast<const float4*>(s);
        float4 v1 = *reinterpret_cast<const float4*>(s + 4);
        short8 fr;
        fr[0] = (short)f2bf(v0.x); fr[1] = (short)f2bf(v0.y);
        fr[2] = (short)f2bf(v0.z); fr[3] = (short)f2bf(v0.w);
        fr[4] = (short)f2bf(v1.x); fr[5] = (short)f2bf(v1.y);
        fr[6] = (short)f2bf(v1.z); fr[7] = (short)f2bf(v1.w);
        *reinterpret_cast<short8*>(&hA[ks * 512 + l * 8]) = fr;
    }
    __syncthreads();

    const short* baseU = upack + (size_t)w * 64 * 512;
    const short* baseW = wpack + (size_t)w * 64 * 512;

#pragma unroll 1
    for (int t = 0; t < T_; ++t) {
        float4v acc[8];
#pragma unroll
        for (int i = 0; i < 8; ++i) acc[i] = (float4v){0.f, 0.f, 0.f, 0.f};

        {
            int bb = b0 + col;
            int k = w * 32 + rg * 8;
            const float* s = x + ((size_t)bb * T_ + t) * 256 + k;
            float4 v0 = *reinterpret_cast<const float4*>(s);
            float4 v1 = *reinterpret_cast<const float4*>(s + 4);
            short8 fr;
            fr[0] = (short)f2bf(v0.x); fr[1] = (short)f2bf(v0.y);
            fr[2] = (short)f2bf(v0.z); fr[3] = (short)f2bf(v0.w);
            fr[4] = (short)f2bf(v1.x); fr[5] = (short)f2bf(v1.y);
            fr[6] = (short)f2bf(v1.z); fr[7] = (short)f2bf(v1.w);
            *reinterpret_cast<short8*>(&xA[w * 512 + l * 8]) = fr;
            __syncthreads();
        }

#pragma unroll
        for (int ks = 0; ks < 8; ++ks) {
            short8 a = *reinterpret_cast<const short8*>(&hA[ks * 512 + l * 8]);
#pragma unroll
            for (int c8 = 0; c8 < 8; ++c8) {
                short8 bfr = *reinterpret_cast<const short8*>(baseU + (size_t)(ks * 8 + c8) * 512 + l * 8);
                acc[c8] = __builtin_amdgcn_mfma_f32_16x16x32_bf16(a, bfr, acc[c8], 0, 0, 0);
            }
        }
#pragma unroll
        for (int ks = 0; ks < 8; ++ks) {
            short8 a = *reinterpret_cast<const short8*>(&xA[ks * 512 + l * 8]);
#pragma unroll
            for (int c8 = 0; c8 < 8; ++c8) {
                short8 bfr = *reinterpret_cast<const short8*>(baseW + (size_t)(ks * 8 + c8) * 512 + l * 8);
                acc[c8] = __builtin_amdgcn_mfma_f32_16x16x32_bf16(a, bfr, acc[c8], 0, 0, 0);
            }
        }
        __syncthreads();

#pragma unroll
        for (int h = 0; h < 2; ++h)
#pragma unroll
            for (int j = 0; j < 4; ++j) {
                float zf = acc[h * 4 + 0][j] + bias[0][h];
                float zi = acc[h * 4 + 1][j] + bias[1][h];
                float zc = acc[h * 4 + 2][j] + bias[2][h];
                float zo = acc[h * 4 + 3][j] + bias[3][h];
                float fg = sigm(zf), ig = sigm(zi), og = sigm(zo);
                float cg = tanh_f(zc);
                float cn = fg * cst[h][j] + ig * cg;
                cst[h][j] = cn;
                float hn = og * tanh_f(cn);

                int bb = b0 + rg * 4 + j;
                int u = w * 32 + h * 16 + col;
                out[((size_t)bb * T_ + t) * 256 + u] = hn;
                if (t == T_ - 1) {
                    out[HALL + (size_t)bb * 256 + u] = hn;
                    out[HALL + (size_t)B_ * U_ + (size_t)bb * 256 + u] = cn;
                }
                int ks2 = u >> 5;
                int s2 = (rg * 4 + j) + 16 * ((u >> 3) & 3);
                hA[ks2 * 512 + s2 * 8 + (u & 7)] = (short)f2bf(hn);
            }
        __syncthreads();
    }
}

extern "C" void kernel_launch(void* const* d_in, const int* in_sizes, int n_in,
                              void* d_out, int out_size, void* d_ws, size_t ws_size,
                              hipStream_t stream) {
    const float* x  = (const float*)d_in[0];
    const float* h0 = (const float*)d_in[1];
    const float* c0 = (const float*)d_in[2];
    const float* Wf = (const float*)d_in[3];
    const float* Uf = (const float*)d_in[4];
    const float* bf = (const float*)d_in[5];
    const float* Wi = (const float*)d_in[6];
    const float* Ui = (const float*)d_in[7];
    const float* bi = (const float*)d_in[8];
    const float* Wc = (const float*)d_in[9];
    const float* Uc = (const float*)d_in[10];
    const float* bc = (const float*)d_in[11];
    const float* Wo = (const float*)d_in[12];
    const float* Uo = (const float*)d_in[13];
    const float* bo = (const float*)d_in[14];

    short* ws    = (short*)d_ws;
    short* upack = ws;                 // 512 KB
    short* wpack = ws + 262144;        // 512 KB
    short* zx    = ws + 524288;        // 268.4 MB (bf16 [T][B][U][4])

    const size_t need = 1048576ull + (size_t)B_ * T_ * U_ * 4 * 2;
    const bool fused = ws_size < need;

    hipLaunchKernelGGL(pack_kernel, dim3(256), dim3(256), 0, stream,
                       Uf, Ui, Uc, Uo, Wf, Wi, Wc, Wo, ws);

    float* out = (float*)d_out;
    if (!fused) {
        hipLaunchKernelGGL(proj_kernel, dim3((B_ * T_) / 64), dim3(512), 0, stream,
                           x, wpack, bf, bi, bc, bo, zx);
        hipLaunchKernelGGL(lstm_scan_res, dim3(8), dim3(512), 0, stream,
                           h0, c0, upack, zx, out);
    } else {
        hipLaunchKernelGGL(lstm_scan_fused, dim3(8), dim3(512), 0, stream,
                           x, h0, c0, bf, bi, bc, bo, upack, wpack, out);
    }
}

// Round 9
// 6921.920 us; speedup vs baseline: 1.1749x; 1.1749x over previous
//
#include <hip/hip_runtime.h>
#include <hip/hip_bf16.h>

// CustomLSTM: B=128, T=1024, D=256, U=256, fp32 in/out.
// Round 9: weights resident in AGPRs.
// Evidence R2-R8: compiler caps this kernel at 128 ARCH VGPRs and spills any
// pinned "+v" values to (L2-resident) scratch -> per-step reload = rounds 2-5
// L2 stream all over again. Fix: pin weight chunks with constraint "+a" ->
// they live in the AGPR half of the unified file (MFMA reads B directly from
// AGPR, ISA sec.10). AGPR side has no other users -> no spill pressure.
//  - NLDS=18 chunks/wave in LDS (144 KB) + 2x8 KB hA = 160 KB.
//  - NAGPR=44 chunks/wave in AGPRs (176 regs).
//  - NSTREAM=2 chunks (q=62,63) streamed from L2/step (16 KB/block, trivial).
//  - arch VGPR working set ~70 (16 acc + frags + addrs) -- fits under 80.
//  - fast v_rcp/v_exp elementwise, gate-phase split, hA double-buffer kept.
// 8 blocks x 16 batches; no inter-block communication anywhere.

#define B_ 128
#define T_ 1024
#define D_ 256
#define U_ 256

#define NLDS  18         // chunks per wave in LDS (144 KB block total)
#define NAGPR 44         // chunks per wave in AGPRs (176 regs, "+a"-pinned)
// chunks q = 62,63 streamed from L2 each step

#define HALL ((size_t)B_ * T_ * U_)

using short8  = __attribute__((ext_vector_type(8))) short;   // 8 bf16 (4 regs)
using float4v = __attribute__((ext_vector_type(4))) float;   // 4 fp32 acc

__device__ inline unsigned short f2bf(float f) {
    unsigned int u = __float_as_uint(f);
    unsigned int r = (u + 0x7FFFu + ((u >> 16) & 1u)) >> 16;
    return (unsigned short)r;
}
__device__ inline float bflo(unsigned int v) { return __uint_as_float(v << 16); }
__device__ inline float bfhi(unsigned int v) { return __uint_as_float(v & 0xffff0000u); }

// 1-instruction transcendentals.
__device__ __forceinline__ float fexp2(float x) {
    float r; asm("v_exp_f32 %0, %1" : "=v"(r) : "v"(x)); return r;
}
__device__ __forceinline__ float frcp(float x) {
    float r; asm("v_rcp_f32 %0, %1" : "=v"(r) : "v"(x)); return r;
}
__device__ __forceinline__ float sigm(float z) {
    return frcp(1.0f + fexp2(-1.44269504f * z));
}
__device__ __forceinline__ float tanh_f(float z) {
    return 1.0f - 2.0f * frcp(1.0f + fexp2(2.88539008f * z));
}

// ---------------------------------------------------------------------------
// Pack 8 matrices [256][256] fp32 (row k, col u) into bf16 MFMA B-fragments.
// chunk = (w*8 + ks)*8 + c8,  c8 = h*4 + g  (h = u-half, g = gate f/i/c/o).
// Lane l of chunk holds  M[k = ks*32 + (l>>4)*8 + j][u = w*32 + h*16 + (l&15)].
// pack0 = Uf,Ui,Uc,Uo (recurrent); pack1 (+262144) = Wf,Wi,Wc,Wo (input proj)
// ---------------------------------------------------------------------------
__global__ __launch_bounds__(256) void pack_kernel(
    const float* __restrict__ Uf, const float* __restrict__ Ui,
    const float* __restrict__ Uc, const float* __restrict__ Uo,
    const float* __restrict__ Wf, const float* __restrict__ Wi,
    const float* __restrict__ Wc, const float* __restrict__ Wo,
    short* __restrict__ ws)
{
    int q = blockIdx.x * 256 + threadIdx.x;      // 0..65535
    int p     = q >> 15;
    int rem   = q & 32767;
    int chunk = rem >> 6;                         // 0..511
    int l     = rem & 63;
    int c8 = chunk & 7;
    int g  = c8 & 3;
    int h  = c8 >> 2;
    int ks = (chunk >> 3) & 7;
    int w  = chunk >> 6;

    const float* mats[8] = {Uf, Ui, Uc, Uo, Wf, Wi, Wc, Wo};
    const float* M = mats[p * 4 + g];

    int u = w * 32 + h * 16 + (l & 15);
    int k = ks * 32 + ((l >> 4) << 3);
    const float* s = M + (size_t)k * 256 + u;

    short8 fr;
#pragma unroll
    for (int j = 0; j < 8; ++j) fr[j] = (short)f2bf(s[(size_t)j * 256]);

    short* dst = ws + (size_t)p * 262144 + (size_t)chunk * 512 + l * 8;
    *reinterpret_cast<short8*>(dst) = fr;
}

// ---------------------------------------------------------------------------
// proj: zx[t][b][u][g] (bf16, bias folded fp32) = x @ W* + b
// ---------------------------------------------------------------------------
__global__ __launch_bounds__(512, 2) void proj_kernel(
    const float* __restrict__ x, const short* __restrict__ wpack,
    const float* __restrict__ bfv, const float* __restrict__ biv,
    const float* __restrict__ bcv, const float* __restrict__ bov,
    short* __restrict__ zx)
{
    __shared__ short aF[4 * 8 * 512];  // 32KB
    const int tid = threadIdx.x;
    const int w = tid >> 6, l = tid & 63;
    const long m0 = (long)blockIdx.x * 64;

#pragma unroll
    for (int rep = 0; rep < 4; ++rep) {
        int slot = tid + rep * 512;
        int ms = slot >> 9;
        int rem = slot & 511;
        int ks = rem >> 6;
        int ll = rem & 63;
        long mm = m0 + ms * 16 + (ll & 15);
        int k = ks * 32 + ((ll >> 4) << 3);
        const float* s = x + (size_t)mm * 256 + k;
        float4 v0 = *reinterpret_cast<const float4*>(s);
        float4 v1 = *reinterpret_cast<const float4*>(s + 4);
        short8 fr;
        fr[0] = (short)f2bf(v0.x); fr[1] = (short)f2bf(v0.y);
        fr[2] = (short)f2bf(v0.z); fr[3] = (short)f2bf(v0.w);
        fr[4] = (short)f2bf(v1.x); fr[5] = (short)f2bf(v1.y);
        fr[6] = (short)f2bf(v1.z); fr[7] = (short)f2bf(v1.w);
        *reinterpret_cast<short8*>(&aF[(ms * 8 + ks) * 512 + ll * 8]) = fr;
    }
    __syncthreads();

    float4v acc[4][8];
#pragma unroll
    for (int ms = 0; ms < 4; ++ms)
#pragma unroll
        for (int c8 = 0; c8 < 8; ++c8) acc[ms][c8] = (float4v){0.f, 0.f, 0.f, 0.f};

    const short* base = wpack + (size_t)w * 64 * 512;
#pragma unroll
    for (int ks = 0; ks < 8; ++ks) {
        short8 a[4];
#pragma unroll
        for (int ms = 0; ms < 4; ++ms)
            a[ms] = *reinterpret_cast<const short8*>(&aF[(ms * 8 + ks) * 512 + l * 8]);
#pragma unroll
        for (int c8 = 0; c8 < 8; ++c8) {
            short8 bfr = *reinterpret_cast<const short8*>(base + (size_t)(ks * 8 + c8) * 512 + l * 8);
#pragma unroll
            for (int ms = 0; ms < 4; ++ms)
                acc[ms][c8] = __builtin_amdgcn_mfma_f32_16x16x32_bf16(a[ms], bfr, acc[ms][c8], 0, 0, 0);
        }
    }

#pragma unroll
    for (int ms = 0; ms < 4; ++ms)
#pragma unroll
        for (int h = 0; h < 2; ++h)
#pragma unroll
            for (int j = 0; j < 4; ++j) {
                size_t mm = (size_t)(m0 + ms * 16 + ((l >> 4) << 2) + j);
                int u = w * 32 + h * 16 + (l & 15);
                size_t b = mm >> 10;          // mm = b*T + t
                size_t t = mm & 1023;
                unsigned int g0 = f2bf(acc[ms][h * 4 + 0][j] + bfv[u]);
                unsigned int g1 = f2bf(acc[ms][h * 4 + 1][j] + biv[u]);
                unsigned int g2 = f2bf(acc[ms][h * 4 + 2][j] + bcv[u]);
                unsigned int g3 = f2bf(acc[ms][h * 4 + 3][j] + bov[u]);
                uint2 v;
                v.x = g0 | (g1 << 16);
                v.y = g2 | (g3 << 16);
                *reinterpret_cast<uint2*>(zx + (t * B_ + b) * 1024 + (size_t)u * 4) = v;
            }
}

// ---------------------------------------------------------------------------
// Elementwise LSTM gate phase for one u-half: 4 outputs (j=0..3).
// ---------------------------------------------------------------------------
__device__ __forceinline__ void ew4(
    int t, const float4v ac[4], const uint2 zc[4], float* csth,
    short* dst, int raddr, float* __restrict__ out_t, const int* ooff,
    float* __restrict__ out, int bb0, int u)
{
#pragma unroll
    for (int j = 0; j < 4; ++j) {
        uint2 v = zc[j];
        float zf = ac[0][j] + bflo(v.x);
        float zi = ac[1][j] + bfhi(v.x);
        float zg = ac[2][j] + bflo(v.y);
        float zo = ac[3][j] + bfhi(v.y);
        float fg = sigm(zf), ig = sigm(zi), og = sigm(zo);
        float cg = tanh_f(zg);
        float cn = fg * csth[j] + ig * cg;
        csth[j] = cn;
        float hn = og * tanh_f(cn);

        out_t[ooff[j]] = hn;
        if (t == T_ - 1) {
            int bb = bb0 + j;
            out[HALL + (size_t)bb * 256 + u] = hn;
            out[HALL + (size_t)B_ * U_ + (size_t)bb * 256 + u] = cn;
        }
        dst[raddr + j * 8] = (short)f2bf(hn);
    }
}

// One full LSTM step: reads h A-frags from src, writes new ones to dst.
__device__ __forceinline__ void lstm_step(
    int t, const short* src, short* dst, const short* wl,
    const short8 (&wa)[NAGPR], const short* baseU,
    const short* __restrict__ zx, float* __restrict__ out,
    float (&cst)[2][4],
    const int* zoffA, const int* zoffB, const int* ooffA, const int* ooffB,
    int rA, int rB, int b0, int w, int l, int rg, int u0)
{
    const short* zx_t = zx + (size_t)t * (B_ * 1024);
    float* out_t = out + (size_t)t * 256;
    const int bb0 = b0 + rg * 4;

    // stream the 2 non-resident chunks (q=62,63; half B, ks=7, g=2,3) early:
    // ~600+ cycles of MFMA/elementwise before first use.
    short8 s62 = *reinterpret_cast<const short8*>(baseU + (size_t)62 * 512);
    short8 s63 = *reinterpret_cast<const short8*>(baseU + (size_t)63 * 512);

    uint2 zcA[4];
#pragma unroll
    for (int j = 0; j < 4; ++j)
        zcA[j] = *reinterpret_cast<const uint2*>(zx_t + zoffA[j]);

    // ---- half A: u-low 16 cols, gates f,i,c,o (q = ks*8 + g) ----
    float4v ac[4];
#pragma unroll
    for (int g = 0; g < 4; ++g) ac[g] = (float4v){0.f, 0.f, 0.f, 0.f};
#pragma unroll
    for (int ks = 0; ks < 8; ++ks) {
        short8 a = *reinterpret_cast<const short8*>(&src[ks * 512 + l * 8]);
#pragma unroll
        for (int g = 0; g < 4; ++g) {
            const int q = ks * 8 + g;
            short8 bv;
            if (q < NLDS)
                bv = *reinterpret_cast<const short8*>(&wl[(w * NLDS + q) * 512 + l * 8]);
            else
                bv = wa[q - NLDS];            // q < 62 always in half A
            ac[g] = __builtin_amdgcn_mfma_f32_16x16x32_bf16(a, bv, ac[g], 0, 0, 0);
        }
    }

    uint2 zcB[4];
#pragma unroll
    for (int j = 0; j < 4; ++j)
        zcB[j] = *reinterpret_cast<const uint2*>(zx_t + zoffB[j]);

    ew4(t, ac, zcA, cst[0], dst, rA, out_t, ooffA, out, bb0, u0);

    // ---- half B: u-high 16 cols (q = ks*8 + 4 + g) ----
    float4v ac2[4];
#pragma unroll
    for (int g = 0; g < 4; ++g) ac2[g] = (float4v){0.f, 0.f, 0.f, 0.f};
#pragma unroll
    for (int ks = 0; ks < 8; ++ks) {
        short8 a = *reinterpret_cast<const short8*>(&src[ks * 512 + l * 8]);
#pragma unroll
        for (int g = 0; g < 4; ++g) {
            const int q = ks * 8 + 4 + g;
            short8 bv;
            if (q < NLDS)
                bv = *reinterpret_cast<const short8*>(&wl[(w * NLDS + q) * 512 + l * 8]);
            else if (q < NLDS + NAGPR)
                bv = wa[q - NLDS];
            else
                bv = (q == 62) ? s62 : s63;
            ac2[g] = __builtin_amdgcn_mfma_f32_16x16x32_bf16(a, bv, ac2[g], 0, 0, 0);
        }
    }
    ew4(t, ac2, zcB, cst[1], dst, rB, out_t, ooffB, out, bb0, u0 + 16);
}

// ---------------------------------------------------------------------------
// Resident scan. 8 blocks x 512 threads; block owns batches [b0, b0+16).
// q<18: LDS.  18<=q<62: AGPR-pinned.  q=62,63: streamed per step.
// ---------------------------------------------------------------------------
__global__ __launch_bounds__(512, 2) void lstm_scan_res(
    const float* __restrict__ h0, const float* __restrict__ c0,
    const short* __restrict__ upack, const short* __restrict__ zx,
    float* __restrict__ out)
{
    __shared__ short wlds[NLDS * 8 * 512];   // 144 KB weight chunks
    __shared__ short hAa[4096];              // 8 KB h A-fragments (even src)
    __shared__ short hAb[4096];              // 8 KB h A-fragments (odd src)

    const int tid = threadIdx.x;
    const int w = tid >> 6, l = tid & 63;
    const int b0 = blockIdx.x * 16;
    const int col = l & 15, rg = l >> 4;
    const int u0 = w * 32 + col;
    const int u1 = u0 + 16;

    const short* baseU = upack + (size_t)w * 64 * 512 + (size_t)l * 8;
#pragma unroll
    for (int q = 0; q < NLDS; ++q)
        *reinterpret_cast<short8*>(&wlds[((size_t)w * NLDS + q) * 512 + l * 8]) =
            *reinterpret_cast<const short8*>(baseU + (size_t)q * 512);

    // Load 44 chunks and pin them into the ACCUMULATOR register file ("a").
    // AGPRs have no other users in this kernel -> no spill pressure; MFMA
    // reads its B operand directly from AGPRs (ISA sec.10). The arch-VGPR
    // side keeps its 128-reg budget for accs + fragments + addressing.
    short8 wa[NAGPR];
#pragma unroll
    for (int r = 0; r < NAGPR; ++r)
        wa[r] = *reinterpret_cast<const short8*>(baseU + (size_t)(NLDS + r) * 512);
#pragma unroll
    for (int r = 0; r < NAGPR; ++r)
        asm volatile("" : "+a"(wa[r]));

    float cst[2][4];
#pragma unroll
    for (int j = 0; j < 4; ++j) {
        cst[0][j] = c0[(size_t)(b0 + rg * 4 + j) * 256 + u0];
        cst[1][j] = c0[(size_t)(b0 + rg * 4 + j) * 256 + u1];
    }

    int zoffA[4], zoffB[4], ooffA[4], ooffB[4];
#pragma unroll
    for (int j = 0; j < 4; ++j) {
        int bb = b0 + rg * 4 + j;
        zoffA[j] = bb * 1024 + u0 * 4;
        zoffB[j] = bb * 1024 + u1 * 4;
        ooffA[j] = bb * (T_ * 256) + u0;
        ooffB[j] = bb * (T_ * 256) + u1;
    }
    const int rA = (u0 >> 5) * 512 + (rg * 4 + 16 * ((u0 >> 3) & 3)) * 8 + (u0 & 7);
    const int rB = (u1 >> 5) * 512 + (rg * 4 + 16 * ((u1 >> 3) & 3)) * 8 + (u1 & 7);

    // stage h0 as A-fragments into hAa (wave w stages ks-chunk w)
    {
        int ks = w;
        int bb = b0 + col;
        int k = ks * 32 + rg * 8;
        const float* s = h0 + (size_t)bb * 256 + k;
        float4 v0 = *reinterpret_cast<const float4*>(s);
        float4 v1 = *reinterpret_cast<const float4*>(s + 4);
        short8 fr;
        fr[0] = (short)f2bf(v0.x); fr[1] = (short)f2bf(v0.y);
        fr[2] = (short)f2bf(v0.z); fr[3] = (short)f2bf(v0.w);
        fr[4] = (short)f2bf(v1.x); fr[5] = (short)f2bf(v1.y);
        fr[6] = (short)f2bf(v1.z); fr[7] = (short)f2bf(v1.w);
        *reinterpret_cast<short8*>(&hAa[ks * 512 + l * 8]) = fr;
    }
    __syncthreads();

#pragma unroll 1
    for (int t = 0; t < T_; t += 2) {
        lstm_step(t,     hAa, hAb, wlds, wa, baseU, zx, out, cst,
                  zoffA, zoffB, ooffA, ooffB, rA, rB, b0, w, l, rg, u0);
        __syncthreads();
        lstm_step(t + 1, hAb, hAa, wlds, wa, baseU, zx, out, cst,
                  zoffA, zoffB, ooffA, ooffB, rA, rB, b0, w, l, rg, u0);
        __syncthreads();
    }
}

// ---------------------------------------------------------------------------
// Fallback fused scan (workspace too small for zx). Slow but correct.
// ---------------------------------------------------------------------------
__global__ __launch_bounds__(512, 2) void lstm_scan_fused(
    const float* __restrict__ x,
    const float* __restrict__ h0, const float* __restrict__ c0,
    const float* __restrict__ bfv, const float* __restrict__ biv,
    const float* __restrict__ bcv, const float* __restrict__ bov,
    const short* __restrict__ upack, const short* __restrict__ wpack,
    float* __restrict__ out)
{
    __shared__ short hA[4096];
    __shared__ short xA[4096];

    const int tid = threadIdx.x;
    const int w = tid >> 6, l = tid & 63;
    const int b0 = blockIdx.x * 16;
    const int col = l & 15, rg = l >> 4;

    float bias[4][2];
#pragma unroll
    for (int h = 0; h < 2; ++h) {
        int u = w * 32 + h * 16 + col;
        bias[0][h] = bfv[u]; bias[1][h] = biv[u];
        bias[2][h] = bcv[u]; bias[3][h] = bov[u];
    }
    float cst[2][4];
#pragma unroll
    for (int h = 0; h < 2; ++h)
#pragma unroll
        for (int j = 0; j < 4; ++j)
            cst[h][j] = c0[(size_t)(b0 + rg * 4 + j) * 256 + (w * 32 + h * 16 + col)];

    {
        int ks = w;
        int bb = b0 + col;
        int k = ks * 32 + rg * 8;
        const float* s = h0 + (size_t)bb * 256 + k;
        float4 v0 = *reinterpret_cast<const float4*>(s);
        float4 v1 = *reinterpret_cast<const float4*>(s + 4);
        short8 fr;
        fr[0] = (short)f2bf(v0.x); fr[1] = (short)f2bf(v0.y);
        fr[2] = (short)f2bf(v0.z); fr[3] = (short)f2bf(v0.w);
        fr[4] = (short)f2bf(v1.x); fr[5] = (short)f2bf(v1.y);
        fr[6] = (short)f2bf(v1.z); fr[7] = (short)f2bf(v1.w);
        *reinterpret_cast<short8*>(&hA[ks * 512 + l * 8]) = fr;
    }
    __syncthreads();

    const short* baseU = upack + (size_t)w * 64 * 512;
    const short* baseW = wpack + (size_t)w * 64 * 512;

#pragma unroll 1
    for (int t = 0; t < T_; ++t) {
        float4v acc[8];
#pragma unroll
        for (int i = 0; i < 8; ++i) acc[i] = (float4v){0.f, 0.f, 0.f, 0.f};

        {
            int bb = b0 + col;
            int k = w * 32 + rg * 8;
            const float* s = x + ((size_t)bb * T_ + t) * 256 + k;
            float4 v0 = *reinterpret_cast<const float4*>(s);
            float4 v1 = *reinterpret_cast<const float4*>(s + 4);
            short8 fr;
            fr[0] = (short)f2bf(v0.x); fr[1] = (short)f2bf(v0.y);
            fr[2] = (short)f2bf(v0.z); fr[3] = (short)f2bf(v0.w);
            fr[4] = (short)f2bf(v1.x); fr[5] = (short)f2bf(v1.y);
            fr[6] = (short)f2bf(v1.z); fr[7] = (short)f2bf(v1.w);
            *reinterpret_cast<short8*>(&xA[w * 512 + l * 8]) = fr;
            __syncthreads();
        }

#pragma unroll
        for (int ks = 0; ks < 8; ++ks) {
            short8 a = *reinterpret_cast<const short8*>(&hA[ks * 512 + l * 8]);
#pragma unroll
            for (int c8 = 0; c8 < 8; ++c8) {
                short8 bfr = *reinterpret_cast<const short8*>(baseU + (size_t)(ks * 8 + c8) * 512 + l * 8);
                acc[c8] = __builtin_amdgcn_mfma_f32_16x16x32_bf16(a, bfr, acc[c8], 0, 0, 0);
            }
        }
#pragma unroll
        for (int ks = 0; ks < 8; ++ks) {
            short8 a = *reinterpret_cast<const short8*>(&xA[ks * 512 + l * 8]);
#pragma unroll
            for (int c8 = 0; c8 < 8; ++c8) {
                short8 bfr = *reinterpret_cast<const short8*>(baseW + (size_t)(ks * 8 + c8) * 512 + l * 8);
                acc[c8] = __builtin_amdgcn_mfma_f32_16x16x32_bf16(a, bfr, acc[c8], 0, 0, 0);
            }
        }
        __syncthreads();

#pragma unroll
        for (int h = 0; h < 2; ++h)
#pragma unroll
            for (int j = 0; j < 4; ++j) {
                float zf = acc[h * 4 + 0][j] + bias[0][h];
                float zi = acc[h * 4 + 1][j] + bias[1][h];
                float zc = acc[h * 4 + 2][j] + bias[2][h];
                float zo = acc[h * 4 + 3][j] + bias[3][h];
                float fg = sigm(zf), ig = sigm(zi), og = sigm(zo);
                float cg = tanh_f(zc);
                float cn = fg * cst[h][j] + ig * cg;
                cst[h][j] = cn;
                float hn = og * tanh_f(cn);

                int bb = b0 + rg * 4 + j;
                int u = w * 32 + h * 16 + col;
                out[((size_t)bb * T_ + t) * 256 + u] = hn;
                if (t == T_ - 1) {
                    out[HALL + (size_t)bb * 256 + u] = hn;
                    out[HALL + (size_t)B_ * U_ + (size_t)bb * 256 + u] = cn;
                }
                int ks2 = u >> 5;
                int s2 = (rg * 4 + j) + 16 * ((u >> 3) & 3);
                hA[ks2 * 512 + s2 * 8 + (u & 7)] = (short)f2bf(hn);
            }
        __syncthreads();
    }
}

extern "C" void kernel_launch(void* const* d_in, const int* in_sizes, int n_in,
                              void* d_out, int out_size, void* d_ws, size_t ws_size,
                              hipStream_t stream) {
    const float* x  = (const float*)d_in[0];
    const float* h0 = (const float*)d_in[1];
    const float* c0 = (const float*)d_in[2];
    const float* Wf = (const float*)d_in[3];
    const float* Uf = (const float*)d_in[4];
    const float* bf = (const float*)d_in[5];
    const float* Wi = (const float*)d_in[6];
    const float* Ui = (const float*)d_in[7];
    const float* bi = (const float*)d_in[8];
    const float* Wc = (const float*)d_in[9];
    const float* Uc = (const float*)d_in[10];
    const float* bc = (const float*)d_in[11];
    const float* Wo = (const float*)d_in[12];
    const float* Uo = (const float*)d_in[13];
    const float* bo = (const float*)d_in[14];

    short* ws    = (short*)d_ws;
    short* upack = ws;                 // 512 KB
    short* wpack = ws + 262144;        // 512 KB
    short* zx    = ws + 524288;        // 268.4 MB (bf16 [T][B][U][4])

    const size_t need = 1048576ull + (size_t)B_ * T_ * U_ * 4 * 2;
    const bool fused = ws_size < need;

    hipLaunchKernelGGL(pack_kernel, dim3(256), dim3(256), 0, stream,
                       Uf, Ui, Uc, Uo, Wf, Wi, Wc, Wo, ws);

    float* out = (float*)d_out;
    if (!fused) {
        hipLaunchKernelGGL(proj_kernel, dim3((B_ * T_) / 64), dim3(512), 0, stream,
                           x, wpack, bf, bi, bc, bo, zx);
        hipLaunchKernelGGL(lstm_scan_res, dim3(8), dim3(512), 0, stream,
                           h0, c0, upack, zx, out);
    } else {
        hipLaunchKernelGGL(lstm_scan_fused, dim3(8), dim3(512), 0, stream,
                           x, h0, c0, bf, bi, bc, bo, upack, wpack, out);
    }
}

// Round 10
// 3858.130 us; speedup vs baseline: 2.1079x; 1.7941x over previous
//
#include <hip/hip_runtime.h>
#include <hip/hip_bf16.h>

// CustomLSTM: B=128, T=1024, D=256, U=256, fp32 in/out.
// Round 10: LDS-resident weights via 4-way U split + inter-block h exchange.
// R2-R9 post-mortem: the compiler refuses register residency in every form
// (launch bounds, waves_per_eu, "+v"/"+a" pins) -> 128 VGPRs + scratch/L2
// re-stream every step. LDS allocation is guaranteed, so make residency an
// LDS property: 32 blocks x 256 thr; block (g,j) = batch-group g (16) x
// u-slice j (64 cols, 4 gates) -> weights 128 KB fully in LDS.
// Siblings {g,j=0..3} exchange h slices each step through d_ws using
// device-scope relaxed atomics (L3-coherent, no L2 fence cost) + per-block
// monotonic flags. Group = {g, g+8, g+16, g+24} so siblings likely share an
// XCD L2 (speed heuristic only; atomics are correct on any mapping).
// Register pressure ~70 VGPRs -> nothing left for the RA to sabotage.

#define B_ 128
#define T_ 1024
#define D_ 256
#define U_ 256

#define HALL ((size_t)B_ * T_ * U_)

// d_ws layout (in shorts):
//   upack : 0        .. 262143   (512 KB)  U* bf16 B-fragment chunks
//   wpack : 262144   .. 524287   (512 KB)  W* bf16 B-fragment chunks
//   zx    : 524288   .. +134217727 (268 MB) [t][b][u*4+g] bf16
//   hex   : 134742016 .. +65535  (128 KB)  [g][parity][16][256] bf16
//   flags : short offset 134807552 (as int*), 32 ints
#define HEX_OFF   134742016ull
#define FLAGS_OFF 134807552ull

using short8  = __attribute__((ext_vector_type(8))) short;   // 8 bf16 (4 regs)
using float4v = __attribute__((ext_vector_type(4))) float;   // 4 fp32 acc

__device__ inline unsigned short f2bf(float f) {
    unsigned int u = __float_as_uint(f);
    unsigned int r = (u + 0x7FFFu + ((u >> 16) & 1u)) >> 16;
    return (unsigned short)r;
}
__device__ inline float bflo(unsigned int v) { return __uint_as_float(v << 16); }
__device__ inline float bfhi(unsigned int v) { return __uint_as_float(v & 0xffff0000u); }

__device__ __forceinline__ float fexp2(float x) {
    float r; asm("v_exp_f32 %0, %1" : "=v"(r) : "v"(x)); return r;
}
__device__ __forceinline__ float frcp(float x) {
    float r; asm("v_rcp_f32 %0, %1" : "=v"(r) : "v"(x)); return r;
}
__device__ __forceinline__ float sigm(float z) {
    return frcp(1.0f + fexp2(-1.44269504f * z));
}
__device__ __forceinline__ float tanh_f(float z) {
    return 1.0f - 2.0f * frcp(1.0f + fexp2(2.88539008f * z));
}

// ---------------------------------------------------------------------------
// Pack 8 matrices [256][256] fp32 into bf16 MFMA B-fragment chunks.
// chunk = (w8*8 + ks)*8 + h*4 + g ; lane l of chunk holds
//   M[k = ks*32 + (l>>4)*8 + j][u = w8*32 + h*16 + (l&15)]
// pack0 = Uf,Ui,Uc,Uo ; pack1 (+262144) = Wf,Wi,Wc,Wo
// ---------------------------------------------------------------------------
__global__ __launch_bounds__(256) void pack_kernel(
    const float* __restrict__ Uf, const float* __restrict__ Ui,
    const float* __restrict__ Uc, const float* __restrict__ Uo,
    const float* __restrict__ Wf, const float* __restrict__ Wi,
    const float* __restrict__ Wc, const float* __restrict__ Wo,
    short* __restrict__ ws)
{
    int q = blockIdx.x * 256 + threadIdx.x;      // 0..65535
    int p     = q >> 15;
    int rem   = q & 32767;
    int chunk = rem >> 6;                         // 0..511
    int l     = rem & 63;
    int c8 = chunk & 7;
    int g  = c8 & 3;
    int h  = c8 >> 2;
    int ks = (chunk >> 3) & 7;
    int w  = chunk >> 6;

    const float* mats[8] = {Uf, Ui, Uc, Uo, Wf, Wi, Wc, Wo};
    const float* M = mats[p * 4 + g];

    int u = w * 32 + h * 16 + (l & 15);
    int k = ks * 32 + ((l >> 4) << 3);
    const float* s = M + (size_t)k * 256 + u;

    short8 fr;
#pragma unroll
    for (int j = 0; j < 8; ++j) fr[j] = (short)f2bf(s[(size_t)j * 256]);

    short* dst = ws + (size_t)p * 262144 + (size_t)chunk * 512 + l * 8;
    *reinterpret_cast<short8*>(dst) = fr;
}

// ---------------------------------------------------------------------------
// proj: zx[t][b][u][g] (bf16, bias folded fp32) = x @ W* + b
// ---------------------------------------------------------------------------
__global__ __launch_bounds__(512, 2) void proj_kernel(
    const float* __restrict__ x, const short* __restrict__ wpack,
    const float* __restrict__ bfv, const float* __restrict__ biv,
    const float* __restrict__ bcv, const float* __restrict__ bov,
    short* __restrict__ zx)
{
    __shared__ short aF[4 * 8 * 512];  // 32KB
    const int tid = threadIdx.x;
    const int w = tid >> 6, l = tid & 63;
    const long m0 = (long)blockIdx.x * 64;

#pragma unroll
    for (int rep = 0; rep < 4; ++rep) {
        int slot = tid + rep * 512;
        int ms = slot >> 9;
        int rem = slot & 511;
        int ks = rem >> 6;
        int ll = rem & 63;
        long mm = m0 + ms * 16 + (ll & 15);
        int k = ks * 32 + ((ll >> 4) << 3);
        const float* s = x + (size_t)mm * 256 + k;
        float4 v0 = *reinterpret_cast<const float4*>(s);
        float4 v1 = *reinterpret_cast<const float4*>(s + 4);
        short8 fr;
        fr[0] = (short)f2bf(v0.x); fr[1] = (short)f2bf(v0.y);
        fr[2] = (short)f2bf(v0.z); fr[3] = (short)f2bf(v0.w);
        fr[4] = (short)f2bf(v1.x); fr[5] = (short)f2bf(v1.y);
        fr[6] = (short)f2bf(v1.z); fr[7] = (short)f2bf(v1.w);
        *reinterpret_cast<short8*>(&aF[(ms * 8 + ks) * 512 + ll * 8]) = fr;
    }
    __syncthreads();

    float4v acc[4][8];
#pragma unroll
    for (int ms = 0; ms < 4; ++ms)
#pragma unroll
        for (int c8 = 0; c8 < 8; ++c8) acc[ms][c8] = (float4v){0.f, 0.f, 0.f, 0.f};

    const short* base = wpack + (size_t)w * 64 * 512;
#pragma unroll
    for (int ks = 0; ks < 8; ++ks) {
        short8 a[4];
#pragma unroll
        for (int ms = 0; ms < 4; ++ms)
            a[ms] = *reinterpret_cast<const short8*>(&aF[(ms * 8 + ks) * 512 + l * 8]);
#pragma unroll
        for (int c8 = 0; c8 < 8; ++c8) {
            short8 bfr = *reinterpret_cast<const short8*>(base + (size_t)(ks * 8 + c8) * 512 + l * 8);
#pragma unroll
            for (int ms = 0; ms < 4; ++ms)
                acc[ms][c8] = __builtin_amdgcn_mfma_f32_16x16x32_bf16(a[ms], bfr, acc[ms][c8], 0, 0, 0);
        }
    }

#pragma unroll
    for (int ms = 0; ms < 4; ++ms)
#pragma unroll
        for (int h = 0; h < 2; ++h)
#pragma unroll
            for (int j = 0; j < 4; ++j) {
                size_t mm = (size_t)(m0 + ms * 16 + ((l >> 4) << 2) + j);
                int u = w * 32 + h * 16 + (l & 15);
                size_t b = mm >> 10;          // mm = b*T + t
                size_t t = mm & 1023;
                unsigned int g0 = f2bf(acc[ms][h * 4 + 0][j] + bfv[u]);
                unsigned int g1 = f2bf(acc[ms][h * 4 + 1][j] + biv[u]);
                unsigned int g2 = f2bf(acc[ms][h * 4 + 2][j] + bcv[u]);
                unsigned int g3 = f2bf(acc[ms][h * 4 + 3][j] + bov[u]);
                uint2 v;
                v.x = g0 | (g1 << 16);
                v.y = g2 | (g3 << 16);
                *reinterpret_cast<uint2*>(zx + (t * B_ + b) * 1024 + (size_t)u * 4) = v;
            }
}

// ---------------------------------------------------------------------------
// Exchange scan: 32 blocks x 256 threads. Block (g = bid&7, j = bid>>3):
// batches [16g, 16g+16), u-cols [64j, 64j+64), all 4 gates; weights in LDS.
// ---------------------------------------------------------------------------
__global__ __launch_bounds__(256, 1) void lstm_scan_x(
    const float* __restrict__ h0, const float* __restrict__ c0,
    const short* __restrict__ upack, const short* __restrict__ zx,
    unsigned int* hex, int* flags, float* __restrict__ out)
{
    __shared__ short wl[128 * 512];   // 128 KB: chunk c = w*32 + ks*4 + gate
    __shared__ short hL[16 * 264];    // 8.25 KB staged h rows, padded to 264

    const int tid = threadIdx.x;
    const int w = tid >> 6, l = tid & 63;
    const int bid = blockIdx.x;
    const int g = bid & 7, j = bid >> 3;
    const int b0 = g * 16;
    const int rg = l >> 4;
    const int u = j * 64 + w * 16 + (l & 15);    // this thread's u column

    // ---- stage this block's 128 weight chunks into LDS (once) ----
#pragma unroll
    for (int it = 0; it < 16; ++it) {
        int c  = it * 8 + (tid >> 5);             // 0..127
        int w_ = c >> 5, ks = (c >> 2) & 7, gt = c & 3;
        int gq = ((2 * j + (w_ >> 1)) * 8 + ks) * 8 + (w_ & 1) * 4 + gt;
        const short* s = upack + (size_t)gq * 512 + (tid & 31) * 16;
        short* d = wl + (size_t)c * 512 + (tid & 31) * 16;
        *reinterpret_cast<short8*>(d)     = *reinterpret_cast<const short8*>(s);
        *reinterpret_cast<short8*>(d + 8) = *reinterpret_cast<const short8*>(s + 8);
    }

    float cst[4];
#pragma unroll
    for (int jj = 0; jj < 4; ++jj)
        cst[jj] = c0[(size_t)(b0 + rg * 4 + jj) * 256 + u];

    // ---- publish h0 slice into hex parity 0 (device-scope atomics) ----
    {
        int r = tid >> 4, c4 = (tid & 15) * 4;
        const float* s = h0 + (size_t)(b0 + r) * 256 + j * 64 + c4;
        float4 v = *reinterpret_cast<const float4*>(s);
        unsigned int p0 = (unsigned int)f2bf(v.x) | ((unsigned int)f2bf(v.y) << 16);
        unsigned int p1 = (unsigned int)f2bf(v.z) | ((unsigned int)f2bf(v.w) << 16);
        unsigned int* d = hex + (((g * 2 + 0) * 16 + r) * 256 + j * 64 + c4) / 2;
        __hip_atomic_store(d,     p0, __ATOMIC_RELAXED, __HIP_MEMORY_SCOPE_AGENT);
        __hip_atomic_store(d + 1, p1, __ATOMIC_RELAXED, __HIP_MEMORY_SCOPE_AGENT);
    }
    asm volatile("s_waitcnt vmcnt(0)" ::: "memory");   // data at L3 before flag
    __syncthreads();
    if (tid == 0)
        __hip_atomic_store(&flags[g * 4 + j], 0, __ATOMIC_RELAXED, __HIP_MEMORY_SCOPE_AGENT);

#pragma unroll 1
    for (int t = 0; t < T_; ++t) {
        // prefetch this step's input projections (plain loads; proj data)
        uint2 zc[4];
        const short* zx_t = zx + (size_t)t * (B_ * 1024);
#pragma unroll
        for (int jj = 0; jj < 4; ++jj)
            zc[jj] = *reinterpret_cast<const uint2*>(
                zx_t + (b0 + rg * 4 + jj) * 1024 + u * 4);

        // wait for all 4 sibling slices of h_t
        if (tid < 4) {
            while (__hip_atomic_load(&flags[g * 4 + tid], __ATOMIC_RELAXED,
                                     __HIP_MEMORY_SCOPE_AGENT) < t)
                __builtin_amdgcn_s_sleep(1);
        }
        __syncthreads();

        // stage h_t (parity t&1) into hL[16][264]
        {
            int r = tid >> 4, c16 = (tid & 15) * 16;
            const unsigned int* s = hex + (((g * 2 + (t & 1)) * 16 + r) * 256 + c16) / 2;
            unsigned int tmp[8];
#pragma unroll
            for (int q = 0; q < 8; ++q)
                tmp[q] = __hip_atomic_load(s + q, __ATOMIC_RELAXED, __HIP_MEMORY_SCOPE_AGENT);
            unsigned int* d = reinterpret_cast<unsigned int*>(&hL[r * 264 + c16]);
#pragma unroll
            for (int q = 0; q < 8; ++q) d[q] = tmp[q];
        }
        __syncthreads();

        // recurrent GEMM: A from hL, B from LDS-resident weights
        float4v acc[4];
#pragma unroll
        for (int gt = 0; gt < 4; ++gt) acc[gt] = (float4v){0.f, 0.f, 0.f, 0.f};
#pragma unroll
        for (int ks = 0; ks < 8; ++ks) {
            short8 a = *reinterpret_cast<const short8*>(
                &hL[(l & 15) * 264 + ks * 32 + (l >> 4) * 8]);
#pragma unroll
            for (int gt = 0; gt < 4; ++gt) {
                short8 bv = *reinterpret_cast<const short8*>(
                    &wl[(size_t)(w * 32 + ks * 4 + gt) * 512 + l * 8]);
                acc[gt] = __builtin_amdgcn_mfma_f32_16x16x32_bf16(a, bv, acc[gt], 0, 0, 0);
            }
        }

        // elementwise (all 4 gates in-lane) + publish h_{t+1}
        const int parn = (t + 1) & 1;
#pragma unroll
        for (int jj = 0; jj < 4; ++jj) {
            uint2 v = zc[jj];
            float zf = acc[0][jj] + bflo(v.x);
            float zi = acc[1][jj] + bfhi(v.x);
            float zg = acc[2][jj] + bflo(v.y);
            float zo = acc[3][jj] + bfhi(v.y);
            float fg = sigm(zf), ig = sigm(zi), og = sigm(zo);
            float cg = tanh_f(zg);
            float cn = fg * cst[jj] + ig * cg;
            cst[jj] = cn;
            float hn = og * tanh_f(cn);

            int b = b0 + rg * 4 + jj;
            out[(size_t)b * (T_ * 256) + (size_t)t * 256 + u] = hn;
            if (t == T_ - 1) {
                out[HALL + (size_t)b * 256 + u] = hn;
                out[HALL + (size_t)B_ * U_ + (size_t)b * 256 + u] = cn;
            }
            if (t < T_ - 1) {
                unsigned int hb = f2bf(hn);
                unsigned int other = (unsigned int)__shfl_xor((int)hb, 1, 64);
                if ((l & 1) == 0) {
                    unsigned int val = hb | (other << 16);
                    unsigned int* d = hex + (((g * 2 + parn) * 16 + (b - b0)) * 256 + u) / 2;
                    __hip_atomic_store(d, val, __ATOMIC_RELAXED, __HIP_MEMORY_SCOPE_AGENT);
                }
            }
        }

        if (t < T_ - 1) {
            asm volatile("s_waitcnt vmcnt(0)" ::: "memory");  // publish complete
            __syncthreads();
            if (tid == 0)
                __hip_atomic_store(&flags[g * 4 + j], t + 1, __ATOMIC_RELAXED,
                                   __HIP_MEMORY_SCOPE_AGENT);
        }
    }
}

// ---------------------------------------------------------------------------
// Fallback fused scan (workspace too small): streams U and W packs from L2
// every step. Slow but correct.
// ---------------------------------------------------------------------------
__global__ __launch_bounds__(512, 2) void lstm_scan_fused(
    const float* __restrict__ x,
    const float* __restrict__ h0, const float* __restrict__ c0,
    const float* __restrict__ bfv, const float* __restrict__ biv,
    const float* __restrict__ bcv, const float* __restrict__ bov,
    const short* __restrict__ upack, const short* __restrict__ wpack,
    float* __restrict__ out)
{
    __shared__ short hA[4096];
    __shared__ short xA[4096];

    const int tid = threadIdx.x;
    const int w = tid >> 6, l = tid & 63;
    const int b0 = blockIdx.x * 16;
    const int col = l & 15, rg = l >> 4;

    float bias[4][2];
#pragma unroll
    for (int h = 0; h < 2; ++h) {
        int u = w * 32 + h * 16 + col;
        bias[0][h] = bfv[u]; bias[1][h] = biv[u];
        bias[2][h] = bcv[u]; bias[3][h] = bov[u];
    }
    float cst[2][4];
#pragma unroll
    for (int h = 0; h < 2; ++h)
#pragma unroll
        for (int j = 0; j < 4; ++j)
            cst[h][j] = c0[(size_t)(b0 + rg * 4 + j) * 256 + (w * 32 + h * 16 + col)];

    {
        int ks = w;
        int bb = b0 + col;
        int k = ks * 32 + rg * 8;
        const float* s = h0 + (size_t)bb * 256 + k;
        float4 v0 = *reinterpret_cast<const float4*>(s);
        float4 v1 = *reinterpret_cast<const float4*>(s + 4);
        short8 fr;
        fr[0] = (short)f2bf(v0.x); fr[1] = (short)f2bf(v0.y);
        fr[2] = (short)f2bf(v0.z); fr[3] = (short)f2bf(v0.w);
        fr[4] = (short)f2bf(v1.x); fr[5] = (short)f2bf(v1.y);
        fr[6] = (short)f2bf(v1.z); fr[7] = (short)f2bf(v1.w);
        *reinterpret_cast<short8*>(&hA[ks * 512 + l * 8]) = fr;
    }
    __syncthreads();

    const short* baseU = upack + (size_t)w * 64 * 512;
    const short* baseW = wpack + (size_t)w * 64 * 512;

#pragma unroll 1
    for (int t = 0; t < T_; ++t) {
        float4v acc[8];
#pragma unroll
        for (int i = 0; i < 8; ++i) acc[i] = (float4v){0.f, 0.f, 0.f, 0.f};

        {
            int bb = b0 + col;
            int k = w * 32 + rg * 8;
            const float* s = x + ((size_t)bb * T_ + t) * 256 + k;
            float4 v0 = *reinterpret_cast<const float4*>(s);
            float4 v1 = *reinterpret_cast<const float4*>(s + 4);
            short8 fr;
            fr[0] = (short)f2bf(v0.x); fr[1] = (short)f2bf(v0.y);
            fr[2] = (short)f2bf(v0.z); fr[3] = (short)f2bf(v0.w);
            fr[4] = (short)f2bf(v1.x); fr[5] = (short)f2bf(v1.y);
            fr[6] = (short)f2bf(v1.z); fr[7] = (short)f2bf(v1.w);
            *reinterpret_cast<short8*>(&xA[w * 512 + l * 8]) = fr;
            __syncthreads();
        }

#pragma unroll
        for (int ks = 0; ks < 8; ++ks) {
            short8 a = *reinterpret_cast<const short8*>(&hA[ks * 512 + l * 8]);
#pragma unroll
            for (int c8 = 0; c8 < 8; ++c8) {
                short8 bfr = *reinterpret_cast<const short8*>(baseU + (size_t)(ks * 8 + c8) * 512 + l * 8);
                acc[c8] = __builtin_amdgcn_mfma_f32_16x16x32_bf16(a, bfr, acc[c8], 0, 0, 0);
            }
        }
#pragma unroll
        for (int ks = 0; ks < 8; ++ks) {
            short8 a = *reinterpret_cast<const short8*>(&xA[ks * 512 + l * 8]);
#pragma unroll
            for (int c8 = 0; c8 < 8; ++c8) {
                short8 bfr = *reinterpret_cast<const short8*>(baseW + (size_t)(ks * 8 + c8) * 512 + l * 8);
                acc[c8] = __builtin_amdgcn_mfma_f32_16x16x32_bf16(a, bfr, acc[c8], 0, 0, 0);
            }
        }
        __syncthreads();

#pragma unroll
        for (int h = 0; h < 2; ++h)
#pragma unroll
            for (int j = 0; j < 4; ++j) {
                float zf = acc[h * 4 + 0][j] + bias[0][h];
                float zi = acc[h * 4 + 1][j] + bias[1][h];
                float zc = acc[h * 4 + 2][j] + bias[2][h];
                float zo = acc[h * 4 + 3][j] + bias[3][h];
                float fg = sigm(zf), ig = sigm(zi), og = sigm(zo);
                float cg = tanh_f(zc);
                float cn = fg * cst[h][j] + ig * cg;
                cst[h][j] = cn;
                float hn = og * tanh_f(cn);

                int bb = b0 + rg * 4 + j;
                int u = w * 32 + h * 16 + col;
                out[((size_t)bb * T_ + t) * 256 + u] = hn;
                if (t == T_ - 1) {
                    out[HALL + (size_t)bb * 256 + u] = hn;
                    out[HALL + (size_t)B_ * U_ + (size_t)bb * 256 + u] = cn;
                }
                int ks2 = u >> 5;
                int s2 = (rg * 4 + j) + 16 * ((u >> 3) & 3);
                hA[ks2 * 512 + s2 * 8 + (u & 7)] = (short)f2bf(hn);
            }
        __syncthreads();
    }
}

extern "C" void kernel_launch(void* const* d_in, const int* in_sizes, int n_in,
                              void* d_out, int out_size, void* d_ws, size_t ws_size,
                              hipStream_t stream) {
    const float* x  = (const float*)d_in[0];
    const float* h0 = (const float*)d_in[1];
    const float* c0 = (const float*)d_in[2];
    const float* Wf = (const float*)d_in[3];
    const float* Uf = (const float*)d_in[4];
    const float* bf = (const float*)d_in[5];
    const float* Wi = (const float*)d_in[6];
    const float* Ui = (const float*)d_in[7];
    const float* bi = (const float*)d_in[8];
    const float* Wc = (const float*)d_in[9];
    const float* Uc = (const float*)d_in[10];
    const float* bc = (const float*)d_in[11];
    const float* Wo = (const float*)d_in[12];
    const float* Uo = (const float*)d_in[13];
    const float* bo = (const float*)d_in[14];

    short* ws    = (short*)d_ws;
    short* upack = ws;                      // 512 KB
    short* wpack = ws + 262144;             // 512 KB
    short* zx    = ws + 524288;             // 268.4 MB
    unsigned int* hex = (unsigned int*)(ws + HEX_OFF);   // 128 KB
    int* flags   = (int*)(ws + FLAGS_OFF);               // 128 B

    const size_t need = FLAGS_OFF * 2 + 128;
    const bool fused = ws_size < need;

    hipLaunchKernelGGL(pack_kernel, dim3(256), dim3(256), 0, stream,
                       Uf, Ui, Uc, Uo, Wf, Wi, Wc, Wo, ws);

    float* out = (float*)d_out;
    if (!fused) {
        hipLaunchKernelGGL(proj_kernel, dim3((B_ * T_) / 64), dim3(512), 0, stream,
                           x, wpack, bf, bi, bc, bo, zx);
        hipLaunchKernelGGL(lstm_scan_x, dim3(32), dim3(256), 0, stream,
                           h0, c0, upack, zx, hex, flags, out);
    } else {
        hipLaunchKernelGGL(lstm_scan_fused, dim3(8), dim3(512), 0, stream,
                           x, h0, c0, bf, bi, bc, bo, upack, wpack, out);
    }
}